// Round 8
// baseline (802.539 us; speedup 1.0000x reference)
//
#include <hip/hip_runtime.h>
#include <stdint.h>

#define N_ATOMS 100000
#define NS 4
#define NE 8
#define D0 384
#define D1 160
#define D2 128
#define D3 96
#define TW 32                                 // atoms per WAVE tile
#define BUCKET_CAP 32768

// ---- workspace layout (bytes) ----
#define IDX_OFF_B 256
#define IDX_CAP (NS*BUCKET_CAP)               // 131072 ints
#define W1B_OFF (IDX_OFF_B + IDX_CAP*4)
#define W1_TOT (NS*NE*D0*D1)
#define W2_TOT (NS*NE*D1*D2)
#define W3_TOT (NS*NE*D2*D3)
#define W2B_OFF (W1B_OFF + W1_TOT*2)
#define W3B_OFF (W2B_OFF + W2_TOT*2)

// LDS strides (halves): 4-row q-step = 4*stride*2 bytes; 172 -> 344B = 24 banks,
// 140 -> 280B = 6*... both give distinct per-quad bank offsets -> <=2-way on writes.
#define S1STR 172
#define S2STR 140

typedef __attribute__((ext_vector_type(8))) _Float16 h8v;
typedef __attribute__((ext_vector_type(4))) float f4v;

__device__ __forceinline__ unsigned short f2h(float x){
    _Float16 h = (_Float16)x;
    return *(unsigned short*)&h;
}

// jax.nn.celu(x, 0.1) = x>0 ? x : 0.1*expm1(x/0.1)
__device__ __forceinline__ float celu01(float v){
    return v > 0.f ? v : 0.1f * (__expf(fminf(v, 0.f) * 10.f) - 1.f);
}

__global__ void k_init(int* hdr, int* idx, float* out){
    int i = blockIdx.x * blockDim.x + threadIdx.x;
    if (i < IDX_CAP) idx[i] = 0;
    if (i < 32) hdr[i] = 0;
    if (i == 0) out[0] = 0.f;
}

__global__ __launch_bounds__(256) void k_scatter(const int* __restrict__ species,
                                                 int* __restrict__ hdr,
                                                 int* __restrict__ idx){
    __shared__ int lc[NS];
    __shared__ int lb[NS];
    int tid = threadIdx.x;
    if (tid < NS) lc[tid] = 0;
    __syncthreads();
    int i = blockIdx.x * 256 + tid;
    int s = 0, r = 0;
    bool valid = (i < N_ATOMS);
    if (valid){
        s = species[i];
        r = atomicAdd(&lc[s], 1);
    }
    __syncthreads();
    if (tid < NS) lb[tid] = atomicAdd(&hdr[tid], lc[tid]);
    __syncthreads();
    if (valid) idx[s * BUCKET_CAP + lb[s] + r] = i;
}

__global__ void k_scan(int* hdr){
    int tb = 0;
    hdr[16] = 0;
    for (int s = 0; s < 4; s++){
        hdr[8 + s] = s * BUCKET_CAP;
        int tiles = (hdr[s] + TW - 1) / TW;
        tb += tiles;
        hdr[17 + s] = tb;
    }
    hdr[21] = (tb + 7) >> 3;                  // tiles per XCD class
}

// W1..W3 fp32 -> fp16 in MFMA-B-fragment order: [net][nt][kt][lane][j]
__global__ void k_convert(const float* __restrict__ W1, const float* __restrict__ W2,
                          const float* __restrict__ W3,
                          unsigned short* __restrict__ W1b, unsigned short* __restrict__ W2b,
                          unsigned short* __restrict__ W3b){
    int i = blockIdx.x * blockDim.x + threadIdx.x;
    if (i < W1_TOT){
        int net = i / (D0*D1);
        int r   = i % (D0*D1);
        int j = r & 7, lane = (r >> 3) & 63, kt = (r >> 9) % 12, nt = r / 6144;
        int k = kt*32 + (lane >> 4)*8 + j;
        int n = nt*16 + (lane & 15);
        W1b[i] = f2h(W1[(net*D0 + k)*D1 + n]);
    } else if (i < W1_TOT + W2_TOT){
        int i2 = i - W1_TOT;
        int net = i2 / (D1*D2);
        int r   = i2 % (D1*D2);
        int j = r & 7, lane = (r >> 3) & 63, kt = (r >> 9) % 5, nt = r / 2560;
        int k = kt*32 + (lane >> 4)*8 + j;
        int n = nt*16 + (lane & 15);
        W2b[i2] = f2h(W2[(net*D1 + k)*D2 + n]);
    } else if (i < W1_TOT + W2_TOT + W3_TOT){
        int i3 = i - W1_TOT - W2_TOT;
        int net = i3 / (D2*D3);
        int r   = i3 % (D2*D3);
        int j = r & 7, lane = (r >> 3) & 63, kt = (r >> 9) % 4, nt = r / 2048;
        int k = kt*32 + (lane >> 4)*8 + j;
        int n = nt*16 + (lane & 15);
        W3b[i3] = f2h(W3[(net*D2 + k)*D3 + n]);
    }
}

// Barrier-free MLP: one WAVE = one 32-atom tile (2 MFMA m-tiles per B-frag).
// Register plan @ __launch_bounds__(256,2) [cap 256]: A1=96, A2=80, A3=32;
// peak live (layer 2) ~210 -> no spill. Weight L2 traffic halved vs TW=16.
__global__ __launch_bounds__(256, 2) void k_mlp(
    const float* __restrict__ aev, const int* __restrict__ hdr, const int* __restrict__ idx,
    const unsigned short* __restrict__ W1b, const unsigned short* __restrict__ W2b,
    const unsigned short* __restrict__ W3b,
    const float* __restrict__ b1, const float* __restrict__ b2, const float* __restrict__ b3,
    const float* __restrict__ W4, const float* __restrict__ b4, float* __restrict__ out)
{
    __shared__ __align__(16) unsigned short sX1[4][TW][S1STR];   // 44032 B
    __shared__ __align__(16) unsigned short sX2[4][TW][S2STR];   // 35840 B

    int tid = threadIdx.x;
    int lane = tid & 63, wid = tid >> 6;
    int total = hdr[20];
    int chunk = hdr[21];
    int xcls = blockIdx.x & 7;
    int j = (blockIdx.x >> 3) * 4 + wid;
    if (j >= chunk) return;
    int tileId = xcls * chunk + j;
    if (tileId >= total) return;

    int s = 0;
    while (s < 3 && tileId >= hdr[17 + s]) s++;
    int t       = tileId - hdr[16 + s];
    int count   = hdr[s];
    int rowBase = t * TW;
    const int* myIdx = idx + s * BUCKET_CAP + rowBase;

    int m = lane & 15, quad = lane >> 4;
    unsigned short (*X1)[S1STR] = sX1[wid];
    unsigned short (*X2)[S2STR] = sX2[wid];

    // ---- layer-1 A fragments from global AEV (fp32->fp16), e-invariant, 96 VGPRs ----
    h8v A1[2][12];
    #pragma unroll
    for (int mt = 0; mt < 2; mt++){
        int atom = myIdx[mt*16 + m];          // padded slots -> atom 0 (masked at end)
        const float* ap = aev + (size_t)atom * D0 + quad*8;
        #pragma unroll
        for (int kt = 0; kt < 12; kt++){
            float4 u = *(const float4*)(ap + kt*32);
            float4 v = *(const float4*)(ap + kt*32 + 4);
            h8v f;
            f[0] = (_Float16)u.x; f[1] = (_Float16)u.y; f[2] = (_Float16)u.z; f[3] = (_Float16)u.w;
            f[4] = (_Float16)v.x; f[5] = (_Float16)v.y; f[6] = (_Float16)v.z; f[7] = (_Float16)v.w;
            A1[mt][kt] = f;
        }
    }

    float e0[4] = {0.f,0.f,0.f,0.f};
    float e1[4] = {0.f,0.f,0.f,0.f};

    #pragma unroll 1
    for (int e = 0; e < NE; e++){
        int net = s * NE + e;

        // ---------- layer 1: A1(regs) [K=384] -> X1 [N=160], depth-1 B prefetch ----------
        {
            const unsigned short* wf = W1b + (size_t)net * (D0*D1) + lane*8;
            #pragma unroll 1
            for (int nt = 0; nt < 10; nt++){
                float bi = b1[net*D1 + nt*16 + m];
                f4v a0 = {bi, bi, bi, bi}, a1 = a0;
                const unsigned short* bp = wf + nt*6144;
                h8v B = *(const h8v*)(bp);
                #pragma unroll
                for (int kt = 0; kt < 12; kt++){
                    h8v nB;
                    if (kt < 11) nB = *(const h8v*)(bp + (kt+1)*512);
                    a0 = __builtin_amdgcn_mfma_f32_16x16x32_f16(A1[0][kt], B, a0, 0, 0, 0);
                    a1 = __builtin_amdgcn_mfma_f32_16x16x32_f16(A1[1][kt], B, a1, 0, 0, 0);
                    B = nB;
                }
                #pragma unroll
                for (int r = 0; r < 4; r++){
                    X1[quad*4 + r][nt*16 + m]      = f2h(celu01(a0[r]));
                    X1[16 + quad*4 + r][nt*16 + m] = f2h(celu01(a1[r]));
                }
            }
        }

        // ---------- layer 2: X1 [K=160] -> X2 [N=128], A2 resident (80 VGPR) ----------
        {
            h8v A2[2][5];
            #pragma unroll
            for (int mt = 0; mt < 2; mt++)
                #pragma unroll
                for (int kt = 0; kt < 5; kt++)
                    A2[mt][kt] = *(const h8v*)&X1[mt*16 + m][kt*32 + quad*8];
            const unsigned short* wf = W2b + (size_t)net * (D1*D2) + lane*8;
            #pragma unroll 1
            for (int nt = 0; nt < 8; nt++){
                float bi = b2[net*D2 + nt*16 + m];
                f4v a0 = {bi, bi, bi, bi}, a1 = a0;
                const unsigned short* bp = wf + nt*2560;
                #pragma unroll
                for (int kt = 0; kt < 5; kt++){
                    h8v B = *(const h8v*)(bp + kt*512);
                    a0 = __builtin_amdgcn_mfma_f32_16x16x32_f16(A2[0][kt], B, a0, 0, 0, 0);
                    a1 = __builtin_amdgcn_mfma_f32_16x16x32_f16(A2[1][kt], B, a1, 0, 0, 0);
                }
                #pragma unroll
                for (int r = 0; r < 4; r++){
                    X2[quad*4 + r][nt*16 + m]      = f2h(celu01(a0[r]));
                    X2[16 + quad*4 + r][nt*16 + m] = f2h(celu01(a1[r]));
                }
            }
        }

        // ---------- layer 3 + 4 fused: X2 [K=128] -> per-atom energies (regs) ----------
        {
            h8v A3[2][4];
            #pragma unroll
            for (int mt = 0; mt < 2; mt++)
                #pragma unroll
                for (int kt = 0; kt < 4; kt++)
                    A3[mt][kt] = *(const h8v*)&X2[mt*16 + m][kt*32 + quad*8];
            const unsigned short* wf = W3b + (size_t)net * (D2*D3) + lane*8;
            const float* w4 = W4 + net * D3;
            #pragma unroll 1
            for (int nt = 0; nt < 6; nt++){
                float bi = b3[net*D3 + nt*16 + m];
                f4v a0 = {bi, bi, bi, bi}, a1 = a0;
                const unsigned short* bp = wf + nt*2048;
                #pragma unroll
                for (int kt = 0; kt < 4; kt++){
                    h8v B = *(const h8v*)(bp + kt*512);
                    a0 = __builtin_amdgcn_mfma_f32_16x16x32_f16(A3[0][kt], B, a0, 0, 0, 0);
                    a1 = __builtin_amdgcn_mfma_f32_16x16x32_f16(A3[1][kt], B, a1, 0, 0, 0);
                }
                float w = w4[nt*16 + m];
                #pragma unroll
                for (int r = 0; r < 4; r++){
                    float v0 = celu01(a0[r]) * w;
                    v0 += __shfl_xor(v0, 1, 16);
                    v0 += __shfl_xor(v0, 2, 16);
                    v0 += __shfl_xor(v0, 4, 16);
                    v0 += __shfl_xor(v0, 8, 16);
                    e0[r] += v0;
                    float v1 = celu01(a1[r]) * w;
                    v1 += __shfl_xor(v1, 1, 16);
                    v1 += __shfl_xor(v1, 2, 16);
                    v1 += __shfl_xor(v1, 4, 16);
                    v1 += __shfl_xor(v1, 8, 16);
                    e1[r] += v1;
                }
            }
        }
    }

    // ---- final: mask padded atoms, reduce 32 atoms, one atomic per wave ----
    {
        int nValid = count - rowBase; if (nValid > TW) nValid = TW; if (nValid < 0) nValid = 0;
        int a0i = quad*4;
        float tot = 0.f;
        #pragma unroll
        for (int r = 0; r < 4; r++){
            tot += (a0i + r      < nValid) ? e0[r] : 0.f;
            tot += (16 + a0i + r < nValid) ? e1[r] : 0.f;
        }
        tot += __shfl_xor(tot, 16, 64);       // sum the 4 quad-groups
        tot += __shfl_xor(tot, 32, 64);
        if (lane == 0){
            float sb4 = 0.f;
            #pragma unroll
            for (int e = 0; e < NE; e++) sb4 += b4[s*NE + e];
            atomicAdd(out, (tot + (float)nValid * sb4) * 0.125f);
        }
    }
}

extern "C" void kernel_launch(void* const* d_in, const int* in_sizes, int n_in,
                              void* d_out, int out_size, void* d_ws, size_t ws_size,
                              hipStream_t stream){
    const float* aev     = (const float*)d_in[0];
    const int*   species = (const int*)  d_in[1];
    const float* W1 = (const float*)d_in[2];
    const float* b1 = (const float*)d_in[3];
    const float* W2 = (const float*)d_in[4];
    const float* b2 = (const float*)d_in[5];
    const float* W3 = (const float*)d_in[6];
    const float* b3 = (const float*)d_in[7];
    const float* W4 = (const float*)d_in[8];
    const float* b4 = (const float*)d_in[9];
    float* out = (float*)d_out;

    int* hdr = (int*)d_ws;
    int* idx = (int*)((char*)d_ws + IDX_OFF_B);
    unsigned short* W1b = (unsigned short*)((char*)d_ws + W1B_OFF);
    unsigned short* W2b = (unsigned short*)((char*)d_ws + W2B_OFF);
    unsigned short* W3b = (unsigned short*)((char*)d_ws + W3B_OFF);

    k_init   <<<(IDX_CAP + 255)/256, 256, 0, stream>>>(hdr, idx, out);
    k_scatter<<<(N_ATOMS + 255)/256, 256, 0, stream>>>(species, hdr, idx);
    k_scan   <<<1, 1, 0, stream>>>(hdr);
    int convTot = W1_TOT + W2_TOT + W3_TOT;
    k_convert<<<(convTot + 255)/256, 256, 0, stream>>>(W1, W2, W3, W1b, W2b, W3b);
    // max tiles = 3125+3 -> chunk <= 391 -> 8 classes * ceil(391/4)=98 blocks; use 800
    k_mlp    <<<800, 256, 0, stream>>>(aev, hdr, idx, W1b, W2b, W3b,
                                       b1, b2, b3, W4, b4, out);
}

// Round 9
// 603.071 us; speedup vs baseline: 1.3308x; 1.3308x over previous
//
#include <hip/hip_runtime.h>
#include <stdint.h>

#define N_ATOMS 100000
#define NS 4
#define NE 8
#define D0 384
#define D1 160
#define D2 128
#define D3 96
#define TW 32                                 // atoms per WAVE tile
#define BUCKET_CAP 32768

// ---- workspace layout (bytes) ----
#define IDX_OFF_B 256
#define IDX_CAP (NS*BUCKET_CAP)               // 131072 ints
#define W1B_OFF (IDX_OFF_B + IDX_CAP*4)
#define W1_TOT (NS*NE*D0*D1)
#define W2_TOT (NS*NE*D1*D2)
#define W3_TOT (NS*NE*D2*D3)
#define W2B_OFF (W1B_OFF + W1_TOT*2)
#define W3B_OFF (W2B_OFF + W2_TOT*2)

// LDS strides (halves) — measured 0 bank conflicts at R8 with these.
#define S1STR 172
#define S2STR 140

typedef __attribute__((ext_vector_type(8))) _Float16 h8v;
typedef __attribute__((ext_vector_type(4))) float f4v;

__device__ __forceinline__ unsigned short f2h(float x){
    _Float16 h = (_Float16)x;
    return *(unsigned short*)&h;
}

// jax.nn.celu(x, 0.1) = x>0 ? x : 0.1*expm1(x/0.1)
__device__ __forceinline__ float celu01(float v){
    return v > 0.f ? v : 0.1f * (__expf(fminf(v, 0.f) * 10.f) - 1.f);
}

__global__ void k_init(int* hdr, int* idx, float* out){
    int i = blockIdx.x * blockDim.x + threadIdx.x;
    if (i < IDX_CAP) idx[i] = 0;
    if (i < 32) hdr[i] = 0;
    if (i == 0) out[0] = 0.f;
}

__global__ __launch_bounds__(256) void k_scatter(const int* __restrict__ species,
                                                 int* __restrict__ hdr,
                                                 int* __restrict__ idx){
    __shared__ int lc[NS];
    __shared__ int lb[NS];
    int tid = threadIdx.x;
    if (tid < NS) lc[tid] = 0;
    __syncthreads();
    int i = blockIdx.x * 256 + tid;
    int s = 0, r = 0;
    bool valid = (i < N_ATOMS);
    if (valid){
        s = species[i];
        r = atomicAdd(&lc[s], 1);
    }
    __syncthreads();
    if (tid < NS) lb[tid] = atomicAdd(&hdr[tid], lc[tid]);
    __syncthreads();
    if (valid) idx[s * BUCKET_CAP + lb[s] + r] = i;
}

__global__ void k_scan(int* hdr){
    int tb = 0;
    hdr[16] = 0;
    for (int s = 0; s < 4; s++){
        hdr[8 + s] = s * BUCKET_CAP;
        int tiles = (hdr[s] + TW - 1) / TW;
        tb += tiles;
        hdr[17 + s] = tb;
    }
    hdr[21] = (tb + 7) >> 3;                  // tiles per XCD class
}

// W1..W3 fp32 -> fp16 in MFMA-B-fragment order: [net][nt][kt][lane][j]
__global__ void k_convert(const float* __restrict__ W1, const float* __restrict__ W2,
                          const float* __restrict__ W3,
                          unsigned short* __restrict__ W1b, unsigned short* __restrict__ W2b,
                          unsigned short* __restrict__ W3b){
    int i = blockIdx.x * blockDim.x + threadIdx.x;
    if (i < W1_TOT){
        int net = i / (D0*D1);
        int r   = i % (D0*D1);
        int j = r & 7, lane = (r >> 3) & 63, kt = (r >> 9) % 12, nt = r / 6144;
        int k = kt*32 + (lane >> 4)*8 + j;
        int n = nt*16 + (lane & 15);
        W1b[i] = f2h(W1[(net*D0 + k)*D1 + n]);
    } else if (i < W1_TOT + W2_TOT){
        int i2 = i - W1_TOT;
        int net = i2 / (D1*D2);
        int r   = i2 % (D1*D2);
        int j = r & 7, lane = (r >> 3) & 63, kt = (r >> 9) % 5, nt = r / 2560;
        int k = kt*32 + (lane >> 4)*8 + j;
        int n = nt*16 + (lane & 15);
        W2b[i2] = f2h(W2[(net*D1 + k)*D2 + n]);
    } else if (i < W1_TOT + W2_TOT + W3_TOT){
        int i3 = i - W1_TOT - W2_TOT;
        int net = i3 / (D2*D3);
        int r   = i3 % (D2*D3);
        int j = r & 7, lane = (r >> 3) & 63, kt = (r >> 9) % 4, nt = r / 2048;
        int k = kt*32 + (lane >> 4)*8 + j;
        int n = nt*16 + (lane & 15);
        W3b[i3] = f2h(W3[(net*D2 + k)*D3 + n]);
    }
}

// Barrier-free MLP: one WAVE = one 32-atom tile; LDS-bound at 2 blocks/CU so
// VGPRs are free -> deep B-prefetch (next-nt double buffer) + 4 acc chains.
__global__ __launch_bounds__(256, 2) void k_mlp(
    const float* __restrict__ aev, const int* __restrict__ hdr, const int* __restrict__ idx,
    const unsigned short* __restrict__ W1b, const unsigned short* __restrict__ W2b,
    const unsigned short* __restrict__ W3b,
    const float* __restrict__ b1, const float* __restrict__ b2, const float* __restrict__ b3,
    const float* __restrict__ W4, const float* __restrict__ b4, float* __restrict__ out)
{
    __shared__ __align__(16) unsigned short sX1[4][TW][S1STR];   // 44032 B
    __shared__ __align__(16) unsigned short sX2[4][TW][S2STR];   // 35840 B

    int tid = threadIdx.x;
    int lane = tid & 63, wid = tid >> 6;
    int total = hdr[20];
    int chunk = hdr[21];
    int xcls = blockIdx.x & 7;
    int j = (blockIdx.x >> 3) * 4 + wid;
    if (j >= chunk) return;
    int tileId = xcls * chunk + j;
    if (tileId >= total) return;

    int s = 0;
    while (s < 3 && tileId >= hdr[17 + s]) s++;
    int t       = tileId - hdr[16 + s];
    int count   = hdr[s];
    int rowBase = t * TW;
    const int* myIdx = idx + s * BUCKET_CAP + rowBase;

    int m = lane & 15, quad = lane >> 4;
    unsigned short (*X1)[S1STR] = sX1[wid];
    unsigned short (*X2)[S2STR] = sX2[wid];

    // ---- layer-1 A fragments from global AEV (fp32->fp16), e-invariant, 96 VGPRs ----
    h8v A1[2][12];
    #pragma unroll
    for (int mt = 0; mt < 2; mt++){
        int atom = myIdx[mt*16 + m];          // padded slots -> atom 0 (masked at end)
        const float* ap = aev + (size_t)atom * D0 + quad*8;
        #pragma unroll
        for (int kt = 0; kt < 12; kt++){
            float4 u = *(const float4*)(ap + kt*32);
            float4 v = *(const float4*)(ap + kt*32 + 4);
            h8v f;
            f[0] = (_Float16)u.x; f[1] = (_Float16)u.y; f[2] = (_Float16)u.z; f[3] = (_Float16)u.w;
            f[4] = (_Float16)v.x; f[5] = (_Float16)v.y; f[6] = (_Float16)v.z; f[7] = (_Float16)v.w;
            A1[mt][kt] = f;
        }
    }

    float e0[4] = {0.f,0.f,0.f,0.f};
    float e1[4] = {0.f,0.f,0.f,0.f};

    #pragma unroll 1
    for (int e = 0; e < NE; e++){
        int net = s * NE + e;

        // ---------- layer 1: A1(regs) [K=384] -> X1 [N=160] ----------
        // full next-nt B prefetch (12 frags in flight) + even/odd acc chains
        {
            const unsigned short* wf = W1b + (size_t)net * (D0*D1) + lane*8;
            h8v Bb[2][12];
            #pragma unroll
            for (int kt = 0; kt < 12; kt++) Bb[0][kt] = *(const h8v*)(wf + kt*512);
            #pragma unroll
            for (int nt = 0; nt < 10; nt++){
                int cur = nt & 1, nxt = cur ^ 1;
                if (nt < 9){
                    const unsigned short* bp = wf + (nt+1)*6144;
                    #pragma unroll
                    for (int kt = 0; kt < 12; kt++) Bb[nxt][kt] = *(const h8v*)(bp + kt*512);
                }
                float bi = b1[net*D1 + nt*16 + m];
                f4v a0e = {bi, bi, bi, bi}, a1e = a0e;
                f4v a0o = {0.f,0.f,0.f,0.f}, a1o = a0o;
                #pragma unroll
                for (int kt = 0; kt < 12; kt += 2){
                    a0e = __builtin_amdgcn_mfma_f32_16x16x32_f16(A1[0][kt],   Bb[cur][kt],   a0e, 0, 0, 0);
                    a1e = __builtin_amdgcn_mfma_f32_16x16x32_f16(A1[1][kt],   Bb[cur][kt],   a1e, 0, 0, 0);
                    a0o = __builtin_amdgcn_mfma_f32_16x16x32_f16(A1[0][kt+1], Bb[cur][kt+1], a0o, 0, 0, 0);
                    a1o = __builtin_amdgcn_mfma_f32_16x16x32_f16(A1[1][kt+1], Bb[cur][kt+1], a1o, 0, 0, 0);
                }
                f4v a0 = a0e + a0o, a1 = a1e + a1o;
                #pragma unroll
                for (int r = 0; r < 4; r++){
                    X1[quad*4 + r][nt*16 + m]      = f2h(celu01(a0[r]));
                    X1[16 + quad*4 + r][nt*16 + m] = f2h(celu01(a1[r]));
                }
            }
        }

        // ---------- layer 2: X1 [K=160] -> X2 [N=128] ----------
        {
            h8v A2[2][5];
            #pragma unroll
            for (int mt = 0; mt < 2; mt++)
                #pragma unroll
                for (int kt = 0; kt < 5; kt++)
                    A2[mt][kt] = *(const h8v*)&X1[mt*16 + m][kt*32 + quad*8];
            const unsigned short* wf = W2b + (size_t)net * (D1*D2) + lane*8;
            h8v Bb[2][5];
            #pragma unroll
            for (int kt = 0; kt < 5; kt++) Bb[0][kt] = *(const h8v*)(wf + kt*512);
            #pragma unroll
            for (int nt = 0; nt < 8; nt++){
                int cur = nt & 1, nxt = cur ^ 1;
                if (nt < 7){
                    const unsigned short* bp = wf + (nt+1)*2560;
                    #pragma unroll
                    for (int kt = 0; kt < 5; kt++) Bb[nxt][kt] = *(const h8v*)(bp + kt*512);
                }
                float bi = b2[net*D2 + nt*16 + m];
                f4v a0e = {bi, bi, bi, bi}, a1e = a0e;
                f4v a0o = {0.f,0.f,0.f,0.f}, a1o = a0o;
                #pragma unroll
                for (int kt = 0; kt < 5; kt++){
                    if ((kt & 1) == 0){
                        a0e = __builtin_amdgcn_mfma_f32_16x16x32_f16(A2[0][kt], Bb[cur][kt], a0e, 0, 0, 0);
                        a1e = __builtin_amdgcn_mfma_f32_16x16x32_f16(A2[1][kt], Bb[cur][kt], a1e, 0, 0, 0);
                    } else {
                        a0o = __builtin_amdgcn_mfma_f32_16x16x32_f16(A2[0][kt], Bb[cur][kt], a0o, 0, 0, 0);
                        a1o = __builtin_amdgcn_mfma_f32_16x16x32_f16(A2[1][kt], Bb[cur][kt], a1o, 0, 0, 0);
                    }
                }
                f4v a0 = a0e + a0o, a1 = a1e + a1o;
                #pragma unroll
                for (int r = 0; r < 4; r++){
                    X2[quad*4 + r][nt*16 + m]      = f2h(celu01(a0[r]));
                    X2[16 + quad*4 + r][nt*16 + m] = f2h(celu01(a1[r]));
                }
            }
        }

        // ---------- layer 3 + 4 fused: X2 [K=128] -> per-atom energies (regs) ----------
        {
            h8v A3[2][4];
            #pragma unroll
            for (int mt = 0; mt < 2; mt++)
                #pragma unroll
                for (int kt = 0; kt < 4; kt++)
                    A3[mt][kt] = *(const h8v*)&X2[mt*16 + m][kt*32 + quad*8];
            const unsigned short* wf = W3b + (size_t)net * (D2*D3) + lane*8;
            const float* w4 = W4 + net * D3;
            h8v Bb[2][4];
            #pragma unroll
            for (int kt = 0; kt < 4; kt++) Bb[0][kt] = *(const h8v*)(wf + kt*512);
            #pragma unroll
            for (int nt = 0; nt < 6; nt++){
                int cur = nt & 1, nxt = cur ^ 1;
                if (nt < 5){
                    const unsigned short* bp = wf + (nt+1)*2048;
                    #pragma unroll
                    for (int kt = 0; kt < 4; kt++) Bb[nxt][kt] = *(const h8v*)(bp + kt*512);
                }
                float bi = b3[net*D3 + nt*16 + m];
                f4v a0e = {bi, bi, bi, bi}, a1e = a0e;
                f4v a0o = {0.f,0.f,0.f,0.f}, a1o = a0o;
                #pragma unroll
                for (int kt = 0; kt < 4; kt += 2){
                    a0e = __builtin_amdgcn_mfma_f32_16x16x32_f16(A3[0][kt],   Bb[cur][kt],   a0e, 0, 0, 0);
                    a1e = __builtin_amdgcn_mfma_f32_16x16x32_f16(A3[1][kt],   Bb[cur][kt],   a1e, 0, 0, 0);
                    a0o = __builtin_amdgcn_mfma_f32_16x16x32_f16(A3[0][kt+1], Bb[cur][kt+1], a0o, 0, 0, 0);
                    a1o = __builtin_amdgcn_mfma_f32_16x16x32_f16(A3[1][kt+1], Bb[cur][kt+1], a1o, 0, 0, 0);
                }
                f4v a0 = a0e + a0o, a1 = a1e + a1o;
                float w = w4[nt*16 + m];
                #pragma unroll
                for (int r = 0; r < 4; r++){
                    float v0 = celu01(a0[r]) * w;
                    v0 += __shfl_xor(v0, 1, 16);
                    v0 += __shfl_xor(v0, 2, 16);
                    v0 += __shfl_xor(v0, 4, 16);
                    v0 += __shfl_xor(v0, 8, 16);
                    e0[r] += v0;
                    float v1 = celu01(a1[r]) * w;
                    v1 += __shfl_xor(v1, 1, 16);
                    v1 += __shfl_xor(v1, 2, 16);
                    v1 += __shfl_xor(v1, 4, 16);
                    v1 += __shfl_xor(v1, 8, 16);
                    e1[r] += v1;
                }
            }
        }
    }

    // ---- final: mask padded atoms, reduce 32 atoms, one atomic per wave ----
    {
        int nValid = count - rowBase; if (nValid > TW) nValid = TW; if (nValid < 0) nValid = 0;
        int a0i = quad*4;
        float tot = 0.f;
        #pragma unroll
        for (int r = 0; r < 4; r++){
            tot += (a0i + r      < nValid) ? e0[r] : 0.f;
            tot += (16 + a0i + r < nValid) ? e1[r] : 0.f;
        }
        tot += __shfl_xor(tot, 16, 64);       // sum the 4 quad-groups
        tot += __shfl_xor(tot, 32, 64);
        if (lane == 0){
            float sb4 = 0.f;
            #pragma unroll
            for (int e = 0; e < NE; e++) sb4 += b4[s*NE + e];
            atomicAdd(out, (tot + (float)nValid * sb4) * 0.125f);
        }
    }
}

extern "C" void kernel_launch(void* const* d_in, const int* in_sizes, int n_in,
                              void* d_out, int out_size, void* d_ws, size_t ws_size,
                              hipStream_t stream){
    const float* aev     = (const float*)d_in[0];
    const int*   species = (const int*)  d_in[1];
    const float* W1 = (const float*)d_in[2];
    const float* b1 = (const float*)d_in[3];
    const float* W2 = (const float*)d_in[4];
    const float* b2 = (const float*)d_in[5];
    const float* W3 = (const float*)d_in[6];
    const float* b3 = (const float*)d_in[7];
    const float* W4 = (const float*)d_in[8];
    const float* b4 = (const float*)d_in[9];
    float* out = (float*)d_out;

    int* hdr = (int*)d_ws;
    int* idx = (int*)((char*)d_ws + IDX_OFF_B);
    unsigned short* W1b = (unsigned short*)((char*)d_ws + W1B_OFF);
    unsigned short* W2b = (unsigned short*)((char*)d_ws + W2B_OFF);
    unsigned short* W3b = (unsigned short*)((char*)d_ws + W3B_OFF);

    k_init   <<<(IDX_CAP + 255)/256, 256, 0, stream>>>(hdr, idx, out);
    k_scatter<<<(N_ATOMS + 255)/256, 256, 0, stream>>>(species, hdr, idx);
    k_scan   <<<1, 1, 0, stream>>>(hdr);
    int convTot = W1_TOT + W2_TOT + W3_TOT;
    k_convert<<<(convTot + 255)/256, 256, 0, stream>>>(W1, W2, W3, W1b, W2b, W3b);
    // max tiles = 3125+3 -> chunk <= 391 -> 8 classes * ceil(391/4)=98 blocks; use 800
    k_mlp    <<<800, 256, 0, stream>>>(aev, hdr, idx, W1b, W2b, W3b,
                                       b1, b2, b3, W4, b4, out);
}